// Round 1
// baseline (141.445 us; speedup 1.0000x reference)
//
#include <hip/hip_runtime.h>
#include <stdint.h>

#define BATCH 4
#define NN 4096
#define DD 256
#define TI 128
#define TJ 64
#define JS 2
#define JRANGE (NN / JS)      // 2048
#define NITER (JRANGE / TJ)   // 32
#define OUTW 257

typedef __attribute__((ext_vector_type(8))) short bf16x8;
typedef __attribute__((ext_vector_type(4))) float f32x4;
typedef __attribute__((ext_vector_type(4))) float f4v;
typedef __attribute__((ext_vector_type(8))) short s8v;

__device__ __forceinline__ short f2bf(float f) {
    uint32_t u = __builtin_bit_cast(uint32_t, f);
    u = (u + 0x7fffu + ((u >> 16) & 1u)) >> 16;
    return (short)u;
}

__device__ __forceinline__ void g2l16(const void* g, void* l) {
    __builtin_amdgcn_global_load_lds((const __attribute__((address_space(1))) void*)g,
                                     (__attribute__((address_space(3))) void*)l, 16, 0, 0);
}
__device__ __forceinline__ void g2l4(const void* g, void* l) {
    __builtin_amdgcn_global_load_lds((const __attribute__((address_space(1))) void*)g,
                                     (__attribute__((address_space(3))) void*)l, 4, 0, 0);
}

// ---------------- prep: f32 -> bf16 copy ----------------
__global__ void convert_k(const float* __restrict__ in, short* __restrict__ out) {
    const int n8 = (BATCH * NN * DD) / 8;
    int stride = gridDim.x * blockDim.x;
    for (int i = blockIdx.x * blockDim.x + threadIdx.x; i < n8; i += stride) {
        f4v a = ((const f4v*)in)[2 * i];
        f4v b = ((const f4v*)in)[2 * i + 1];
        s8v o;
        o[0] = f2bf(a[0]); o[1] = f2bf(a[1]); o[2] = f2bf(a[2]); o[3] = f2bf(a[3]);
        o[4] = f2bf(b[0]); o[5] = f2bf(b[1]); o[6] = f2bf(b[2]); o[7] = f2bf(b[3]);
        ((s8v*)out)[i] = o;
    }
}

// ---------------- prep: f32 [B][N][D] -> bf16 [B][D][N] ----------------
__global__ __launch_bounds__(256) void transpose_k(const float* __restrict__ val,
                                                   short* __restrict__ vt) {
    __shared__ float tile[32][33];
    int b = blockIdx.z;
    int d0 = blockIdx.x * 32, n0 = blockIdx.y * 32;
    int tx = threadIdx.x, ty = threadIdx.y;
#pragma unroll
    for (int yy = ty; yy < 32; yy += 8)
        tile[yy][tx] = val[((size_t)b * NN + n0 + yy) * DD + d0 + tx];
    __syncthreads();
#pragma unroll
    for (int yy = ty; yy < 32; yy += 8)
        vt[((size_t)b * DD + d0 + yy) * NN + n0 + tx] = f2bf(tile[tx][yy]);
}

// ---------------- main fused kernel ----------------
// grid: BATCH * (NN/TI) * JS = 256 blocks, 256 threads (4 waves, 32 rows/wave)
// LDS carve (dynamic, 147968 B):
//   Vs [2][64*256] bf16 (XOR-swizzled)   : 65536 B   @ 0
//   Vt [2][256*64] bf16 (XOR-swizzled)   : 65536 B   @ 65536
//   Ss [2][64] f32                       : 512 B     @ 131072
//   Pl [4][32*64] bf16 (per-wave P tile) : 16384 B   @ 131584
__global__ void __launch_bounds__(256, 1) prop_main(const short* __restrict__ vbf,
                                                    const short* __restrict__ vtbf,
                                                    const float* __restrict__ state,
                                                    float* __restrict__ part) {
    extern __shared__ char smem[];
    short* Vs = (short*)(smem);
    short* Vt = (short*)(smem + 65536);
    float* Ss = (float*)(smem + 131072);
    short* Pl = (short*)(smem + 131584);

    const int bid = blockIdx.x;
    const int js = bid & 1;
    const int rb = (bid >> 1) & 31;
    const int b = bid >> 6;
    const int tid = threadIdx.x;
    const int w = tid >> 6, lane = tid & 63;
    const int g = lane >> 4, c = lane & 15;
    const int j0base = js * JRANGE;
    const int ibase = rb * TI + w * 32;

    // resident A fragments: rows ibase..ibase+31, full D
    bf16x8 Af[2][8];
#pragma unroll
    for (int m = 0; m < 2; ++m)
#pragma unroll
        for (int k = 0; k < 8; ++k)
            Af[m][k] = *(const bf16x8*)(vbf + ((size_t)(b * NN + ibase + m * 16 + c) * DD + k * 32 + g * 8));

    f32x4 accO[2][16];
#pragma unroll
    for (int m = 0; m < 2; ++m)
#pragma unroll
        for (int nb = 0; nb < 16; ++nb)
            accO[m][nb] = (f32x4){0.f, 0.f, 0.f, 0.f};
    float vsum[2][4] = {{0.f, 0.f, 0.f, 0.f}, {0.f, 0.f, 0.f, 0.f}};

    auto stage = [&](int t, int pbuf) {
        const int j0 = j0base + t * TJ;
        {
            short* dst = Vs + pbuf * 16384;
#pragma unroll
            for (int it = 0; it < 8; ++it) {
                int idx0 = (w * 8 + it) * 64;
                int idx = idx0 + lane;
                int jj = idx >> 5, ccp = idx & 31;
                int cc = ccp ^ (jj & 7);                 // inverse-swizzled source chunk
                g2l16(vbf + ((size_t)(b * NN + j0 + jj) * DD + cc * 8), dst + idx0 * 8);
            }
        }
        {
            short* dst = Vt + pbuf * 16384;
#pragma unroll
            for (int it = 0; it < 8; ++it) {
                int idx0 = (w * 8 + it) * 64;
                int idx = idx0 + lane;
                int d = idx >> 3, cjp = idx & 7;
                int cj = cjp ^ (d & 7);
                g2l16(vtbf + ((size_t)(b * DD + d) * NN + j0 + cj * 8), dst + idx0 * 8);
            }
        }
        if (w == 0) g2l4(state + b * NN + j0 + lane, Ss + pbuf * 64);
    };

    stage(0, 0);
    __syncthreads();
    int pb = 0;
    for (int t = 0; t < NITER; ++t) {
        if (t + 1 < NITER) stage(t + 1, pb ^ 1);

        const short* VsB = Vs + pb * 16384;
        const short* VtB = Vt + pb * 16384;
        const float* SsB = Ss + pb * 64;
        short* PlW = Pl + w * 2048;

        // ---- S = V_i . V_j^T ----
        f32x4 accS[2][4];
#pragma unroll
        for (int m = 0; m < 2; ++m)
#pragma unroll
            for (int nb = 0; nb < 4; ++nb)
                accS[m][nb] = (f32x4){0.f, 0.f, 0.f, 0.f};

#pragma unroll
        for (int k = 0; k < 8; ++k) {
#pragma unroll
            for (int nb = 0; nb < 4; ++nb) {
                int jj = nb * 16 + c;
                int ccp = (k * 4 + g) ^ (jj & 7);
                bf16x8 bfr = *(const bf16x8*)(VsB + jj * 256 + ccp * 8);
                accS[0][nb] = __builtin_amdgcn_mfma_f32_16x16x32_bf16(Af[0][k], bfr, accS[0][nb], 0, 0, 0);
                accS[1][nb] = __builtin_amdgcn_mfma_f32_16x16x32_bf16(Af[1][k], bfr, accS[1][nb], 0, 0, 0);
            }
        }

        // ---- softsign + state-accum + P -> LDS (per-wave, no barrier) ----
        float stv[4];
#pragma unroll
        for (int nb = 0; nb < 4; ++nb) stv[nb] = SsB[nb * 16 + c];

#pragma unroll
        for (int m = 0; m < 2; ++m)
#pragma unroll
            for (int nb = 0; nb < 4; ++nb)
#pragma unroll
                for (int r = 0; r < 4; ++r) {
                    float s = accS[m][nb][r];
                    float e = s * __builtin_amdgcn_rcpf(1.0f + __builtin_fabsf(s));
                    vsum[m][r] += e * stv[nb];
                    int il = m * 16 + g * 4 + r;
                    int j = nb * 16 + c;
                    PlW[il * 64 + (j ^ ((il & 7) << 3))] = f2bf(e);
                }

        // ---- O += P . V_j ----
#pragma unroll
        for (int kk = 0; kk < 2; ++kk) {
            int il0 = c;
            bf16x8 pa0 = *(const bf16x8*)(PlW + il0 * 64 + ((kk * 32 + g * 8) ^ ((il0 & 7) << 3)));
            int il1 = 16 + c;
            bf16x8 pa1 = *(const bf16x8*)(PlW + il1 * 64 + ((kk * 32 + g * 8) ^ ((il1 & 7) << 3)));
#pragma unroll
            for (int nb = 0; nb < 16; ++nb) {
                int d = nb * 16 + c;
                int cjp = (kk * 4 + g) ^ (d & 7);
                bf16x8 vb = *(const bf16x8*)(VtB + d * 64 + cjp * 8);
                accO[0][nb] = __builtin_amdgcn_mfma_f32_16x16x32_bf16(pa0, vb, accO[0][nb], 0, 0, 0);
                accO[1][nb] = __builtin_amdgcn_mfma_f32_16x16x32_bf16(pa1, vb, accO[1][nb], 0, 0, 0);
            }
        }
        __syncthreads();   // drains vmcnt(0): next buffer staged & this buffer free
        pb ^= 1;
    }

    // ---- epilogue: write partials ----
    float* po = part + (size_t)js * ((size_t)BATCH * NN * OUTW);
#pragma unroll
    for (int m = 0; m < 2; ++m)
#pragma unroll
        for (int nb = 0; nb < 16; ++nb)
#pragma unroll
            for (int r = 0; r < 4; ++r) {
                int row = ibase + m * 16 + g * 4 + r;
                po[((size_t)b * NN + row) * OUTW + nb * 16 + c] = accO[m][nb][r];
            }
#pragma unroll
    for (int m = 0; m < 2; ++m)
#pragma unroll
        for (int r = 0; r < 4; ++r) {
            float v = vsum[m][r];
            v += __shfl_xor(v, 1);
            v += __shfl_xor(v, 2);
            v += __shfl_xor(v, 4);
            v += __shfl_xor(v, 8);
            if (c == 0) {
                int row = ibase + m * 16 + g * 4 + r;
                po[((size_t)b * NN + row) * OUTW + 256] = v;
            }
        }
}

// ---------------- reduce the JS partial sums ----------------
__global__ void reduce_k(const float* __restrict__ part, float* __restrict__ out) {
    const size_t tot4 = ((size_t)BATCH * NN * OUTW) / 4;
    const f4v* p0 = (const f4v*)part;
    const f4v* p1 = (const f4v*)(part + (size_t)BATCH * NN * OUTW);
    f4v* o = (f4v*)out;
    size_t stride = (size_t)gridDim.x * blockDim.x;
    for (size_t i = blockIdx.x * blockDim.x + threadIdx.x; i < tot4; i += stride) {
        f4v x = p0[i];
        f4v y = p1[i];
        o[i] = x + y;
    }
}

extern "C" void kernel_launch(void* const* d_in, const int* in_sizes, int n_in,
                              void* d_out, int out_size, void* d_ws, size_t ws_size,
                              hipStream_t stream) {
    const float* val = (const float*)d_in[0];
    const float* state = (const float*)d_in[1];
    float* out = (float*)d_out;

    const size_t bf_bytes = (size_t)BATCH * NN * DD * 2;       // 8 MiB
    const size_t part_elems = (size_t)BATCH * NN * OUTW;       // 4,210,688
    short* vbf = (short*)d_ws;
    short* vtbf = (short*)((char*)d_ws + bf_bytes);
    float* part = (float*)((char*)d_ws + 2 * bf_bytes);
    if (ws_size < 2 * bf_bytes + (size_t)JS * part_elems * sizeof(float)) return;

    hipFuncSetAttribute((const void*)prop_main, hipFuncAttributeMaxDynamicSharedMemorySize, 147968);

    convert_k<<<1024, 256, 0, stream>>>(val, vbf);
    transpose_k<<<dim3(DD / 32, NN / 32, BATCH), dim3(32, 8), 0, stream>>>(val, vtbf);
    prop_main<<<BATCH * (NN / TI) * JS, 256, 147968, stream>>>(vbf, vtbf, state, part);
    reduce_k<<<1024, 256, 0, stream>>>(part, out);
}

// Round 2
// 101.541 us; speedup vs baseline: 1.3930x; 1.3930x over previous
//
#include <hip/hip_runtime.h>
#include <stdint.h>

#define BATCH 4
#define NN 4096
#define DD 256
#define TI 128
#define TJ 64
#define JS 2
#define JRANGE (NN / JS)      // 2048
#define NITER (JRANGE / TJ)   // 32

#define VS_OFF 0              // 2 x 32768 B (V_j tile, row-major [64][256] bf16, 16B-chunk XOR swizzle)
#define VT_OFF 65536          // 2 x 32768 B (V_j^T tile, [256][64] bf16, swizzled)
#define P_OFF  131072         // 16384 B (shared P [128][64] bf16, swizzled)
#define SS_OFF 147456         // 2 x 256 B (state tile f32)
#define LDS_BYTES 147968

typedef __attribute__((ext_vector_type(8))) short bf16x8;
typedef __attribute__((ext_vector_type(4))) float f32x4;
typedef __attribute__((ext_vector_type(4))) float f4v;
typedef __attribute__((ext_vector_type(8))) short s8v;
typedef __attribute__((ext_vector_type(4))) short s4v;

__device__ __forceinline__ short f2bf(float f) {
    uint32_t u = __builtin_bit_cast(uint32_t, f);
    u = (u + 0x7fffu + ((u >> 16) & 1u)) >> 16;
    return (short)u;
}

__device__ __forceinline__ void g2l16(const void* g, void* l) {
    __builtin_amdgcn_global_load_lds((const __attribute__((address_space(1))) void*)g,
                                     (__attribute__((address_space(3))) void*)l, 16, 0, 0);
}
__device__ __forceinline__ void g2l4(const void* g, void* l) {
    __builtin_amdgcn_global_load_lds((const __attribute__((address_space(1))) void*)g,
                                     (__attribute__((address_space(3))) void*)l, 4, 0, 0);
}

// ---------------- prep: f32 -> bf16 copy ----------------
__global__ void convert_k(const float* __restrict__ in, short* __restrict__ out) {
    const int n8 = (BATCH * NN * DD) / 8;
    int stride = gridDim.x * blockDim.x;
    for (int i = blockIdx.x * blockDim.x + threadIdx.x; i < n8; i += stride) {
        f4v a = ((const f4v*)in)[2 * i];
        f4v b = ((const f4v*)in)[2 * i + 1];
        s8v o;
        o[0] = f2bf(a[0]); o[1] = f2bf(a[1]); o[2] = f2bf(a[2]); o[3] = f2bf(a[3]);
        o[4] = f2bf(b[0]); o[5] = f2bf(b[1]); o[6] = f2bf(b[2]); o[7] = f2bf(b[3]);
        ((s8v*)out)[i] = o;
    }
}

// ---------------- prep: f32 [B][N][D] -> bf16 [B][D][N] ----------------
__global__ __launch_bounds__(256) void transpose_k(const float* __restrict__ val,
                                                   short* __restrict__ vt) {
    __shared__ float tile[32][33];
    int b = blockIdx.z;
    int d0 = blockIdx.x * 32, n0 = blockIdx.y * 32;
    int tx = threadIdx.x, ty = threadIdx.y;
#pragma unroll
    for (int yy = ty; yy < 32; yy += 8)
        tile[yy][tx] = val[((size_t)b * NN + n0 + yy) * DD + d0 + tx];
    __syncthreads();
#pragma unroll
    for (int yy = ty; yy < 32; yy += 8)
        vt[((size_t)b * DD + d0 + yy) * NN + n0 + tx] = f2bf(tile[tx][yy]);
}

// ---------------- main fused kernel ----------------
// grid: BATCH * (NN/TI) * JS = 256 blocks, 512 threads (8 waves)
// wave roles: ig = w&3 -> i-group (32 rows) for S; jh = w>>2 -> j-half for S
//             wr = w&1, wd = w>>1 -> PV sub-tile: rows wr*64.., cols wd*64..
__global__ void __launch_bounds__(512, 2) prop_main(const short* __restrict__ vbf,
                                                    const short* __restrict__ vtbf,
                                                    const float* __restrict__ state,
                                                    float* __restrict__ part,
                                                    float* __restrict__ spart) {
    extern __shared__ char smem[];

    const int bid = blockIdx.x;
    const int js = bid & 1;
    const int rb = (bid >> 1) & 31;
    const int b = bid >> 6;
    const int tid = threadIdx.x;
    const int w = tid >> 6, lane = tid & 63;
    const int g = lane >> 4, c = lane & 15;
    const int ig = w & 3, jh = w >> 2;
    const int wr = w & 1, wd = w >> 1;
    const int r7 = c & 7;
    const int j0base = js * JRANGE;

    // 16B-chunk byte offsets for even/odd k-steps: ((k*4+g)^r7)<<4 = (k>>1)*128 + (k&1 ? xO : xE)
    const int xE = ((((r7 >> 2) << 2) | (g ^ (r7 & 3))) << 4);
    const int xO = (((((r7 >> 2) ^ 1) << 2) | (g ^ (r7 & 3))) << 4);

    // B-operand (V_i rows) resident in registers: rows rb*128 + ig*32 .. +31
    bf16x8 Bf[2][8];
    const size_t irowb = (size_t)b * NN + rb * TI + ig * 32;
#pragma unroll
    for (int m = 0; m < 2; ++m)
#pragma unroll
        for (int k = 0; k < 8; ++k)
            Bf[m][k] = *(const bf16x8*)(vbf + ((irowb + m * 16 + c) * DD + k * 32 + g * 8));

    f32x4 accO[4][4];
#pragma unroll
    for (int mt = 0; mt < 4; ++mt)
#pragma unroll
        for (int dt = 0; dt < 4; ++dt)
            accO[mt][dt] = (f32x4){0.f, 0.f, 0.f, 0.f};
    float vsum[2] = {0.f, 0.f};

    auto stage = [&](int t, int nb) {
        const int j0 = j0base + t * TJ;
        {
            char* dst = smem + VS_OFF + nb * 32768;
#pragma unroll
            for (int p = 0; p < 4; ++p) {
                int ch0 = p * 512 + w * 64;     // wave-uniform chunk base
                int ch = ch0 + lane;
                int row = ch >> 5, cir = ch & 31;
                g2l16(vbf + ((size_t)(b * NN + j0 + row) * DD + ((cir ^ (row & 7)) * 8)),
                      dst + ch0 * 16);
            }
        }
        {
            char* dst = smem + VT_OFF + nb * 32768;
#pragma unroll
            for (int p = 0; p < 4; ++p) {
                int ch0 = p * 512 + w * 64;
                int ch = ch0 + lane;
                int d = ch >> 3, cj = ch & 7;
                g2l16(vtbf + ((size_t)(b * DD + d) * NN + j0 + ((cj ^ (d & 7)) * 8)),
                      dst + ch0 * 16);
            }
        }
        if (w == 0) g2l4(state + b * NN + j0 + lane, smem + SS_OFF + nb * 256);
    };

    stage(0, 0);
    __syncthreads();
    int pb = 0;
    for (int t = 0; t < NITER; ++t) {
        const char* VsB = smem + VS_OFF + pb * 32768;
        const char* VtB = smem + VT_OFF + pb * 32768;
        const char* SsB = smem + SS_OFF + pb * 256;

        // ---- S^T = V_j . V_i^T  (A = V_j from LDS, B = V_i regs) ----
        f32x4 accS[2][2];
#pragma unroll
        for (int jbl = 0; jbl < 2; ++jbl)
#pragma unroll
            for (int m = 0; m < 2; ++m)
                accS[jbl][m] = (f32x4){0.f, 0.f, 0.f, 0.f};

        const char* aRow0 = VsB + (jh * 32 + c) * 512;   // jbl=0 row base; jbl=1 -> +8192
#pragma unroll
        for (int k = 0; k < 8; ++k) {
            const int off = (k >> 1) * 128 + ((k & 1) ? xO : xE);
            bf16x8 a0 = *(const bf16x8*)(aRow0 + off);
            bf16x8 a1 = *(const bf16x8*)(aRow0 + 8192 + off);
            accS[0][0] = __builtin_amdgcn_mfma_f32_16x16x32_bf16(a0, Bf[0][k], accS[0][0], 0, 0, 0);
            accS[0][1] = __builtin_amdgcn_mfma_f32_16x16x32_bf16(a0, Bf[1][k], accS[0][1], 0, 0, 0);
            accS[1][0] = __builtin_amdgcn_mfma_f32_16x16x32_bf16(a1, Bf[0][k], accS[1][0], 0, 0, 0);
            accS[1][1] = __builtin_amdgcn_mfma_f32_16x16x32_bf16(a1, Bf[1][k], accS[1][1], 0, 0, 0);
        }

        // ---- softsign + state-accum + packed P write (b64, swizzled) ----
#pragma unroll
        for (int jbl = 0; jbl < 2; ++jbl) {
            f4v sv = *(const f4v*)(SsB + (jh * 32 + jbl * 16 + g * 4) * 4);
#pragma unroll
            for (int m = 0; m < 2; ++m) {
                s4v pk;
#pragma unroll
                for (int r = 0; r < 4; ++r) {
                    float s = accS[jbl][m][r];
                    float e = s * __builtin_amdgcn_rcpf(1.0f + __builtin_fabsf(s));
                    vsum[m] += e * sv[r];
                    pk[r] = f2bf(e);
                }
                int i = ig * 32 + m * 16 + c;   // P row, i&7 == r7
                *(s4v*)(smem + P_OFF + i * 128 + ((jh * 64 + jbl * 32 + g * 8) ^ (r7 << 4))) = pk;
            }
        }

        __syncthreads();                 // bar1: P visible; nothing outstanding in vmcnt
        if (t + 1 < NITER) stage(t + 1, pb ^ 1);   // latency hides under PV

        // ---- O += P . V_j  (wave sub-tile: 64 rows x 64 cols) ----
        const char* paRow = smem + P_OFF + (wr * 64 + c) * 128;
        const char* vbRow = VtB + (wd * 64 + c) * 128;
#pragma unroll
        for (int kk = 0; kk < 2; ++kk) {
            const int off = kk ? xO : xE;
            bf16x8 pa[4], vb[4];
#pragma unroll
            for (int mt = 0; mt < 4; ++mt) pa[mt] = *(const bf16x8*)(paRow + mt * 2048 + off);
#pragma unroll
            for (int dt = 0; dt < 4; ++dt) vb[dt] = *(const bf16x8*)(vbRow + dt * 2048 + off);
#pragma unroll
            for (int mt = 0; mt < 4; ++mt)
#pragma unroll
                for (int dt = 0; dt < 4; ++dt)
                    accO[mt][dt] = __builtin_amdgcn_mfma_f32_16x16x32_bf16(pa[mt], vb[dt], accO[mt][dt], 0, 0, 0);
        }

        __syncthreads();                 // bar2: stage drained (vmcnt0), P free for next iter
        pb ^= 1;
    }

    // ---- epilogue: delta_val partials ----
    {
        float* po = part + (((size_t)(js * BATCH + b) * NN + rb * TI + wr * 64) * DD) + wd * 64;
#pragma unroll
        for (int mt = 0; mt < 4; ++mt)
#pragma unroll
            for (int dt = 0; dt < 4; ++dt)
#pragma unroll
                for (int r = 0; r < 4; ++r)
                    po[(size_t)(mt * 16 + g * 4 + r) * DD + dt * 16 + c] = accO[mt][dt][r];
    }

    // ---- epilogue: delta_state (reduce over g, then combine jh halves via LDS) ----
#pragma unroll
    for (int m = 0; m < 2; ++m) {
        vsum[m] += __shfl_xor(vsum[m], 16);
        vsum[m] += __shfl_xor(vsum[m], 32);
    }
    float* Xf = (float*)(smem + P_OFF);   // P region is dead now
    if (jh == 1 && lane < 16) {
        Xf[(ig * 2 + 0) * 16 + lane] = vsum[0];
        Xf[(ig * 2 + 1) * 16 + lane] = vsum[1];
    }
    __syncthreads();
    if (jh == 0 && lane < 16) {
        size_t sb = ((size_t)js * BATCH + b) * NN + rb * TI + ig * 32;
#pragma unroll
        for (int m = 0; m < 2; ++m)
            spart[sb + m * 16 + lane] = vsum[m] + Xf[(ig * 2 + m) * 16 + lane];
    }
}

// ---------------- final reduce: out[b,i,0:256] = p0+p1 ; out[b,i,256] = s0+s1 ----------------
__global__ __launch_bounds__(256) void reduce2_k(const float* __restrict__ part,
                                                 const float* __restrict__ spart,
                                                 float* __restrict__ out) {
    const int row = blockIdx.x;           // b*4096 + i
    const int t = threadIdx.x;
    const size_t PS = (size_t)BATCH * NN * DD;
    float v = part[(size_t)row * DD + t] + part[PS + (size_t)row * DD + t];
    out[(size_t)row * 257 + t] = v;
    if (t == 0) {
        const size_t SS = (size_t)BATCH * NN;
        out[(size_t)row * 257 + 256] = spart[row] + spart[SS + row];
    }
}

extern "C" void kernel_launch(void* const* d_in, const int* in_sizes, int n_in,
                              void* d_out, int out_size, void* d_ws, size_t ws_size,
                              hipStream_t stream) {
    const float* val = (const float*)d_in[0];
    const float* state = (const float*)d_in[1];
    float* out = (float*)d_out;

    const size_t bf_bytes = (size_t)BATCH * NN * DD * 2;          // 8 MiB
    const size_t part_bytes = (size_t)JS * BATCH * NN * DD * 4;   // 32 MiB
    const size_t spart_bytes = (size_t)JS * BATCH * NN * 4;       // 128 KiB
    short* vbf = (short*)d_ws;
    short* vtbf = (short*)((char*)d_ws + bf_bytes);
    float* part = (float*)((char*)d_ws + 2 * bf_bytes);
    float* spart = (float*)((char*)d_ws + 2 * bf_bytes + part_bytes);
    if (ws_size < 2 * bf_bytes + part_bytes + spart_bytes) return;

    hipFuncSetAttribute((const void*)prop_main, hipFuncAttributeMaxDynamicSharedMemorySize, LDS_BYTES);

    convert_k<<<1024, 256, 0, stream>>>(val, vbf);
    transpose_k<<<dim3(DD / 32, NN / 32, BATCH), dim3(32, 8), 0, stream>>>(val, vtbf);
    prop_main<<<BATCH * (NN / TI) * JS, 512, LDS_BYTES, stream>>>(vbf, vtbf, state, part, spart);
    reduce2_k<<<BATCH * NN, 256, 0, stream>>>(part, spart, out);
}

// Round 3
// 93.379 us; speedup vs baseline: 1.5148x; 1.0874x over previous
//
#include <hip/hip_runtime.h>
#include <stdint.h>

#define BATCH 4
#define NN 4096
#define DD 256
#define TI 128
#define TJ 64
#define JS 2
#define JRANGE (NN / JS)      // 2048
#define NITER (JRANGE / TJ)   // 32

#define VS_OFF 0              // 2 x 32768 B (V_j tile [64][256] bf16, 16B-chunk XOR swizzle)
#define VT_OFF 65536          // 2 x 32768 B (V_j^T tile [256][64] bf16, swizzled)
#define P_OFF  131072         // 2 x 16384 B (P [128][64] bf16, swizzled, double-buffered)
#define LDS_BYTES 163840      // exactly 160 KiB

typedef __attribute__((ext_vector_type(8))) short bf16x8;
typedef __attribute__((ext_vector_type(4))) float f32x4;
typedef __attribute__((ext_vector_type(4))) float f4v;
typedef __attribute__((ext_vector_type(8))) short s8v;
typedef __attribute__((ext_vector_type(4))) short s4v;

__device__ __forceinline__ short f2bf(float f) {
    uint32_t u = __builtin_bit_cast(uint32_t, f);
    u = (u + 0x7fffu + ((u >> 16) & 1u)) >> 16;
    return (short)u;
}

__device__ __forceinline__ void g2l16(const void* g, void* l) {
    __builtin_amdgcn_global_load_lds((const __attribute__((address_space(1))) void*)g,
                                     (__attribute__((address_space(3))) void*)l, 16, 0, 0);
}

// ---------------- prep: f32 [B][N][D] -> bf16 [B][N][D] and bf16 [B][D][N] (one read of val) ----------------
__global__ __launch_bounds__(256) void prep_k(const float* __restrict__ val,
                                              short* __restrict__ vbf,
                                              short* __restrict__ vt) {
    __shared__ float tile[32][33];
    int b = blockIdx.z;
    int d0 = blockIdx.x * 32, n0 = blockIdx.y * 32;
    int tx = threadIdx.x, ty = threadIdx.y;
#pragma unroll
    for (int yy = ty; yy < 32; yy += 8) {
        float v = val[((size_t)b * NN + n0 + yy) * DD + d0 + tx];
        tile[yy][tx] = v;
        vbf[((size_t)b * NN + n0 + yy) * DD + d0 + tx] = f2bf(v);
    }
    __syncthreads();
#pragma unroll
    for (int yy = ty; yy < 32; yy += 8)
        vt[((size_t)b * DD + d0 + yy) * NN + n0 + tx] = f2bf(tile[tx][yy]);
}

// ---------------- main fused kernel ----------------
// grid: BATCH * (NN/TI) * JS = 256 blocks, 512 threads (8 waves)
// Software pipeline: iter t = { stage Vs(t+1) | S(t) | PV(t-1) | softsign(t)->P[t&1] } bar { stage Vt(t+1) }
__global__ void __launch_bounds__(512, 2) prop_main(const short* __restrict__ vbf,
                                                    const short* __restrict__ vtbf,
                                                    const float* __restrict__ state,
                                                    float* __restrict__ part,
                                                    float* __restrict__ spart) {
    extern __shared__ char smem[];

    const int bid = blockIdx.x;
    const int js = bid & 1;
    const int rb = (bid >> 1) & 31;
    const int b = bid >> 6;
    const int tid = threadIdx.x;
    const int w = tid >> 6, lane = tid & 63;
    const int g = lane >> 4, c = lane & 15;
    const int ig = w & 3, jh = w >> 2;
    const int wr = w & 1, wd = w >> 1;
    const int r7 = c & 7;
    const int j0base = js * JRANGE;

    // 16B-slot byte offsets: ((k*4+g)^r7)<<4 = (k>>1)*128 + (k&1 ? xO : xE)
    const int xE = ((((r7 >> 2) << 2) | (g ^ (r7 & 3))) << 4);
    const int xO = (((((r7 >> 2) ^ 1) << 2) | (g ^ (r7 & 3))) << 4);

    // V_i rows resident in registers (B-operand of S^T)
    bf16x8 Bf[2][8];
    const size_t irowb = (size_t)b * NN + rb * TI + ig * 32;
#pragma unroll
    for (int m = 0; m < 2; ++m)
#pragma unroll
        for (int k = 0; k < 8; ++k)
            Bf[m][k] = *(const bf16x8*)(vbf + ((irowb + m * 16 + c) * DD + k * 32 + g * 8));

    f32x4 accO[4][4];
#pragma unroll
    for (int mt = 0; mt < 4; ++mt)
#pragma unroll
        for (int dt = 0; dt < 4; ++dt)
            accO[mt][dt] = (f32x4){0.f, 0.f, 0.f, 0.f};
    float vsum[2] = {0.f, 0.f};

    auto stageVs = [&](int t, int nb) {
        const int j0 = j0base + t * TJ;
        char* dst = smem + VS_OFF + nb * 32768;
#pragma unroll
        for (int p = 0; p < 4; ++p) {
            int ch0 = p * 512 + w * 64;
            int ch = ch0 + lane;
            int row = ch >> 5, cir = ch & 31;
            g2l16(vbf + ((size_t)(b * NN + j0 + row) * DD + ((cir ^ (row & 7)) * 8)),
                  dst + ch0 * 16);
        }
    };
    auto stageVt = [&](int t, int nb) {
        const int j0 = j0base + t * TJ;
        char* dst = smem + VT_OFF + nb * 32768;
#pragma unroll
        for (int p = 0; p < 4; ++p) {
            int ch0 = p * 512 + w * 64;
            int ch = ch0 + lane;
            int d = ch >> 3, cj = ch & 7;
            g2l16(vtbf + ((size_t)(b * DD + d) * NN + j0 + ((cj ^ (d & 7)) * 8)),
                  dst + ch0 * 16);
        }
    };

    auto pvStep = [&](int slot) {
        const char* paRow = smem + P_OFF + slot * 16384 + (wr * 64 + c) * 128;
        const char* vbRow = smem + VT_OFF + slot * 32768 + (wd * 64 + c) * 128;
        __builtin_amdgcn_s_setprio(1);
#pragma unroll
        for (int kk = 0; kk < 2; ++kk) {
            const int off = kk ? xO : xE;
            bf16x8 pa[4], vb[4];
#pragma unroll
            for (int mt = 0; mt < 4; ++mt) pa[mt] = *(const bf16x8*)(paRow + mt * 2048 + off);
#pragma unroll
            for (int dt = 0; dt < 4; ++dt) vb[dt] = *(const bf16x8*)(vbRow + dt * 2048 + off);
#pragma unroll
            for (int mt = 0; mt < 4; ++mt)
#pragma unroll
                for (int dt = 0; dt < 4; ++dt)
                    accO[mt][dt] = __builtin_amdgcn_mfma_f32_16x16x32_bf16(pa[mt], vb[dt], accO[mt][dt], 0, 0, 0);
        }
        __builtin_amdgcn_s_setprio(0);
    };

    const float* stp = state + b * NN + j0base;

    // prologue: tile 0 into slot 0
    stageVs(0, 0);
    stageVt(0, 0);
    __syncthreads();

    for (int t = 0; t < NITER; ++t) {
        const int cur = t & 1, prv = cur ^ 1;

        // A: issue next Vs stage (slot prv == (t+1)&1; its old reader S(t-1) finished before last barrier)
        if (t + 1 < NITER) stageVs(t + 1, prv);

        // state prefetch for this tile (L2-resident, broadcast within 16-lane groups)
        f4v sv0 = *(const f4v*)(stp + t * TJ + jh * 32 + g * 4);
        f4v sv1 = *(const f4v*)(stp + t * TJ + jh * 32 + 16 + g * 4);

        // ---- S(t): S^T = V_j . V_i^T  (A = V_j from Vs[cur], B = V_i regs) ----
        f32x4 accS[2][2];
#pragma unroll
        for (int jbl = 0; jbl < 2; ++jbl)
#pragma unroll
            for (int m = 0; m < 2; ++m)
                accS[jbl][m] = (f32x4){0.f, 0.f, 0.f, 0.f};

        const char* aRow0 = smem + VS_OFF + cur * 32768 + (jh * 32 + c) * 512;
#pragma unroll
        for (int k = 0; k < 8; ++k) {
            const int off = (k >> 1) * 128 + ((k & 1) ? xO : xE);
            bf16x8 a0 = *(const bf16x8*)(aRow0 + off);
            bf16x8 a1 = *(const bf16x8*)(aRow0 + 8192 + off);
            accS[0][0] = __builtin_amdgcn_mfma_f32_16x16x32_bf16(a0, Bf[0][k], accS[0][0], 0, 0, 0);
            accS[0][1] = __builtin_amdgcn_mfma_f32_16x16x32_bf16(a0, Bf[1][k], accS[0][1], 0, 0, 0);
            accS[1][0] = __builtin_amdgcn_mfma_f32_16x16x32_bf16(a1, Bf[0][k], accS[1][0], 0, 0, 0);
            accS[1][1] = __builtin_amdgcn_mfma_f32_16x16x32_bf16(a1, Bf[1][k], accS[1][1], 0, 0, 0);
        }

        // ---- PV(t-1): O += P . V_j  (reads P[prv], Vt[prv]; independent of S(t)) ----
        if (t > 0) pvStep(prv);

        // ---- softsign(t) + state-accum + packed P write into P[cur] ----
#pragma unroll
        for (int jbl = 0; jbl < 2; ++jbl) {
            f4v sv = jbl ? sv1 : sv0;
#pragma unroll
            for (int m = 0; m < 2; ++m) {
                s4v pk;
#pragma unroll
                for (int r = 0; r < 4; ++r) {
                    float s = accS[jbl][m][r];
                    float e = s * __builtin_amdgcn_rcpf(1.0f + __builtin_fabsf(s));
                    vsum[m] += e * sv[r];
                    pk[r] = f2bf(e);
                }
                int i = ig * 32 + m * 16 + c;
                *(s4v*)(smem + P_OFF + cur * 16384 + i * 128 +
                        ((jh * 64 + jbl * 32 + g * 8) ^ (r7 << 4))) = pk;
            }
        }

        __syncthreads();   // one barrier/iter: P[cur] visible; Vs(t+1) + Vt(t+1)-from-prev-iter drained

        // D: issue next Vt stage (slot prv; its old reader PV(t-1) finished before this barrier;
        //    drains at NEXT iter's barrier, before PV(t+1) consumes it the iter after)
        if (t + 1 < NITER) stageVt(t + 1, prv);
    }

    // epilogue: PV for the last tile (P[(NITER-1)&1] = P[1], Vt[1])
    pvStep((NITER - 1) & 1);

    // ---- delta_val partials ----
    {
        float* po = part + (((size_t)(js * BATCH + b) * NN + rb * TI + wr * 64) * DD) + wd * 64;
#pragma unroll
        for (int mt = 0; mt < 4; ++mt)
#pragma unroll
            for (int dt = 0; dt < 4; ++dt)
#pragma unroll
                for (int r = 0; r < 4; ++r)
                    po[(size_t)(mt * 16 + g * 4 + r) * DD + dt * 16 + c] = accO[mt][dt][r];
    }

    // ---- delta_state partials (reduce over g via shfl, across jh via LDS) ----
#pragma unroll
    for (int m = 0; m < 2; ++m) {
        vsum[m] += __shfl_xor(vsum[m], 16);
        vsum[m] += __shfl_xor(vsum[m], 32);
    }
    float* Xf = (float*)(smem + P_OFF);   // P[0] region is dead now
    __syncthreads();
    if (jh == 1 && lane < 16) {
        Xf[(ig * 2 + 0) * 16 + lane] = vsum[0];
        Xf[(ig * 2 + 1) * 16 + lane] = vsum[1];
    }
    __syncthreads();
    if (jh == 0 && lane < 16) {
        size_t sb = ((size_t)js * BATCH + b) * NN + rb * TI + ig * 32;
#pragma unroll
        for (int m = 0; m < 2; ++m)
            spart[sb + m * 16 + lane] = vsum[m] + Xf[(ig * 2 + m) * 16 + lane];
    }
}

// ---------------- final reduce: out[b,i,0:256] = p0+p1 ; out[b,i,256] = s0+s1 ----------------
__global__ __launch_bounds__(256) void reduce2_k(const float* __restrict__ part,
                                                 const float* __restrict__ spart,
                                                 float* __restrict__ out) {
    const int row = blockIdx.x;           // b*4096 + i
    const int t = threadIdx.x;
    const size_t PS = (size_t)BATCH * NN * DD;
    float v = part[(size_t)row * DD + t] + part[PS + (size_t)row * DD + t];
    out[(size_t)row * 257 + t] = v;
    if (t == 0) {
        const size_t SS = (size_t)BATCH * NN;
        out[(size_t)row * 257 + 256] = spart[row] + spart[SS + row];
    }
}

extern "C" void kernel_launch(void* const* d_in, const int* in_sizes, int n_in,
                              void* d_out, int out_size, void* d_ws, size_t ws_size,
                              hipStream_t stream) {
    const float* val = (const float*)d_in[0];
    const float* state = (const float*)d_in[1];
    float* out = (float*)d_out;

    const size_t bf_bytes = (size_t)BATCH * NN * DD * 2;          // 8 MiB
    const size_t part_bytes = (size_t)JS * BATCH * NN * DD * 4;   // 32 MiB
    const size_t spart_bytes = (size_t)JS * BATCH * NN * 4;       // 128 KiB
    short* vbf = (short*)d_ws;
    short* vtbf = (short*)((char*)d_ws + bf_bytes);
    float* part = (float*)((char*)d_ws + 2 * bf_bytes);
    float* spart = (float*)((char*)d_ws + 2 * bf_bytes + part_bytes);
    if (ws_size < 2 * bf_bytes + part_bytes + spart_bytes) return;

    hipFuncSetAttribute((const void*)prop_main, hipFuncAttributeMaxDynamicSharedMemorySize, LDS_BYTES);

    prep_k<<<dim3(DD / 32, NN / 32, BATCH), dim3(32, 8), 0, stream>>>(val, vbf, vtbf);
    prop_main<<<BATCH * (NN / TI) * JS, 512, LDS_BYTES, stream>>>(vbf, vtbf, state, part, spart);
    reduce2_k<<<BATCH * NN, 256, 0, stream>>>(part, spart, out);
}